// Round 4
// baseline (319.202 us; speedup 1.0000x reference)
//
#include <hip/hip_runtime.h>
#include <hip/hip_bf16.h>
#include <stdint.h>

#define DI __device__ __forceinline__

constexpr int Bn = 64;               // batch
constexpr int S  = 197;              // seq
constexpr int Dm = 768;              // model dim
constexpr int H  = 12;               // heads
constexpr int DH = 64;               // head dim
constexpr int M  = Bn * S;           // 12608 rows
constexpr int SP = 224;              // padded seq for transposed V (7 * 32)
constexpr int MD = M * Dm;           // 9,682,944
constexpr int WN = Dm * Dm;          // 589,824

typedef __attribute__((ext_vector_type(8))) short bf8;   // 8 bf16 = 4 VGPRs
typedef __attribute__((ext_vector_type(4))) float f4;

DI ushort f2bf(float f) {
  union { __hip_bfloat16 b; ushort u; } cv;
  cv.b = __float2bfloat16(f);
  return cv.u;
}

// async global->LDS, 16B per lane; lds base must be wave-uniform
DI void gload_lds16(const void* g, const void* lds) {
  __builtin_amdgcn_global_load_lds(
      (__attribute__((address_space(1))) void*)(uintptr_t)g,
      (__attribute__((address_space(3))) void*)(uint32_t)(uintptr_t)lds,
      16, 0, 0);
}

DI bf8 ld16(const ushort* p) { return *(const bf8*)p; }

// ---------------------------------------------------------------- convert
__global__ __launch_bounds__(256) void convert_all(
    const float4* __restrict__ q,  const float4* __restrict__ k,
    const float4* __restrict__ v,  const float4* __restrict__ wq,
    const float4* __restrict__ wk, const float4* __restrict__ wv,
    const float4* __restrict__ wo,
    ushort4* __restrict__ qb, ushort4* __restrict__ kb,
    ushort4* __restrict__ vb, ushort4* __restrict__ wb) {
  constexpr int NT = MD / 4;
  constexpr int NW = WN / 4;
  int i = blockIdx.x * 256 + threadIdx.x;
  const float4* src; ushort4* dst; int off;
  if (i < NT)            { src = q; dst = qb; off = i; }
  else if (i < 2 * NT)   { src = k; dst = kb; off = i - NT; }
  else if (i < 3 * NT)   { src = v; dst = vb; off = i - 2 * NT; }
  else {
    int j = i - 3 * NT;
    int wsel = j / NW; off = j - wsel * NW;
    src = wsel == 0 ? wq : wsel == 1 ? wk : wsel == 2 ? wv : wo;
    dst = wb + (size_t)wsel * NW;
  }
  float4 f = src[off];
  ushort4 u;
  u.x = f2bf(f.x); u.y = f2bf(f.y); u.z = f2bf(f.z); u.w = f2bf(f.w);
  dst[off] = u;
}

// ---------------------------------------------------------------- 128^2 GEMM, depth-2 prefetch
// C = A * W^T.  A: [M x 768] bf16 row-major, W: [768 x 768] bf16 ([out][in]).
// 4 waves (2x2), per-wave 64x64 output, BK=32, TRIPLE-buffered LDS (48 KiB),
// XOR-swizzled (slot = g ^ ((row>>1)&3)).  Stage buffer t+2 at step t; gate =
// s_waitcnt vmcnt(4) lgkmcnt(0) + one barrier per step (vmcnt(0) only at the
// last step).  Invariant: at gate of step t, outstanding = batches {t, t+1}
// (8 loads); vmcnt(4) retires exactly batch t.  3 blocks/CU.

// stage one 128x32 slab; LDS dest linear, global source pre-swizzled (rule 21)
DI void stage128(const ushort* __restrict__ src, int rowmax, int row0,
                 int kcol0, ushort* lds, int w, int lane) {
#pragma unroll
  for (int l = 0; l < 2; ++l) {
    const int cid = w * 2 + l;            // wave-uniform 0..7
    const int c = cid * 64 + lane;        // chunk 0..511 (4 chunks of 16B/row)
    const int rl = c >> 2;
    int rg = row0 + rl; if (rg > rowmax) rg = rowmax;
    const int k8 = (c & 3) ^ ((rl >> 1) & 3);   // inverse swizzle on source
    gload_lds16(src + (size_t)rg * Dm + kcol0 + k8 * 8, lds + cid * 512);
  }
}

// swizzled fragment read: logical 16B chunk g of row -> slot g ^ ((row>>1)&3)
DI bf8 ldfrag(const ushort* buf, int row, int g) {
  return ld16(buf + row * 32 + ((g ^ ((row >> 1) & 3)) << 3));
}

template <int MODE>
__global__ __launch_bounds__(256, 3) void gemmL(
    const ushort* __restrict__ Ab, const ushort* __restrict__ Wb,
    ushort* __restrict__ OQK, ushort* __restrict__ OV, float* __restrict__ OF) {
  __shared__ __align__(16) ushort As[3 * 128 * 32];   // 24 KiB
  __shared__ __align__(16) ushort Bs[3 * 128 * 32];   // 24 KiB
  constexpr int NT  = 6;       // n-tiles (N = 768)
  constexpr int NWG = 594;     // 99 m-tiles * 6 n-tiles
  const int tid = threadIdx.x, lane = tid & 63, w = tid >> 6;
  const int wr = w >> 1, wc = w & 1;
  const int rsel = lane & 15, g = lane >> 4;

  // bijective XCD swizzle (m204), n-fastest for A-panel L2 reuse
  constexpr int qq = NWG / 8, rr = NWG % 8;
  const int bid = blockIdx.x;
  const int xcd = bid & 7, pos = bid >> 3;
  const int wg = (xcd < rr ? xcd * (qq + 1) : rr * (qq + 1) + (xcd - rr) * qq) + pos;
  const int nt = wg % NT, mt = wg / NT;
  const int n0 = nt * 128, m0 = mt * 128;
  const int z = blockIdx.y;
  const ushort* A = Ab + (size_t)z * MD;
  const ushort* W = Wb + (size_t)z * WN;

  const f4 fz = {0.f, 0.f, 0.f, 0.f};
  f4 acc[4][4];
#pragma unroll
  for (int i = 0; i < 4; i++)
#pragma unroll
    for (int j = 0; j < 4; j++) acc[i][j] = fz;

  // prologue: stage K-steps 0 and 1 (8 loads in flight per wave)
  stage128(A, M - 1, m0, 0,  As,        w, lane);
  stage128(W, 767,   n0, 0,  Bs,        w, lane);
  stage128(A, M - 1, m0, 32, As + 4096, w, lane);
  stage128(W, 767,   n0, 32, Bs + 4096, w, lane);

  int cb = 0;                         // current buffer (kt % 3)
#pragma unroll 3
  for (int kt = 0; kt < 24; ++kt) {
    if (kt == 23) {
      asm volatile("s_waitcnt vmcnt(0) lgkmcnt(0)" ::: "memory");
    } else {
      asm volatile("s_waitcnt vmcnt(4) lgkmcnt(0)" ::: "memory");
    }
    __builtin_amdgcn_s_barrier();
    if (kt < 22) {                    // stage batch kt+2 into buffer (cb+2)%3
      int pb = cb + 2; if (pb >= 3) pb -= 3;
      stage128(A, M - 1, m0, (kt + 2) * 32, As + pb * 4096, w, lane);
      stage128(W, 767,   n0, (kt + 2) * 32, Bs + pb * 4096, w, lane);
    }
    const ushort* cA = As + cb * 4096;
    const ushort* cB = Bs + cb * 4096;
    bf8 a[4], b[4];
#pragma unroll
    for (int i = 0; i < 4; ++i) a[i] = ldfrag(cA, wr * 64 + i * 16 + rsel, g);
#pragma unroll
    for (int j = 0; j < 4; ++j) b[j] = ldfrag(cB, wc * 64 + j * 16 + rsel, g);
#pragma unroll
    for (int i = 0; i < 4; ++i)
#pragma unroll
      for (int j = 0; j < 4; ++j)
        acc[i][j] = __builtin_amdgcn_mfma_f32_16x16x32_bf16(a[i], b[j], acc[i][j], 0, 0, 0);
    ++cb; if (cb == 3) cb = 0;
  }

  // epilogue: C row = (lane>>4)*4+reg (m), col = lane&15 (n)
#pragma unroll
  for (int i = 0; i < 4; i++) {
    const int mb = m0 + wr * 64 + i * 16 + g * 4;
#pragma unroll
    for (int j = 0; j < 4; j++) {
      const int n = n0 + wc * 64 + j * 16 + rsel;
#pragma unroll
      for (int rg = 0; rg < 4; rg++) {
        const int m = mb + rg;
        if (m < M) {
          const float val = acc[i][j][rg];
          if (MODE == 1) {
            OF[(size_t)m * Dm + n] = val;
          } else {
            const int b = m / S, s = m - b * S;
            const int hh = n >> 6, dh = n & 63;
            const ushort bv = f2bf(val);
            if (z < 2)
              OQK[(size_t)z * MD + (((size_t)b * H + hh) * S + s) * DH + dh] = bv;
            else
              OV[(((size_t)b * H + hh) * DH + dh) * SP + s] = bv;
          }
        }
      }
    }
  }
}

// ---------------------------------------------------------------- attention
// one block per (b,h); 4 waves; wave handles q-tiles {w, w+4, w+8, (w==0: 12)}
__global__ __launch_bounds__(256) void attn_fwd(
    const ushort* __restrict__ Qh, const ushort* __restrict__ Kh,
    const ushort* __restrict__ Vt, ushort* __restrict__ xh,
    float* __restrict__ outcls) {
  __shared__ __align__(16) ushort Pl[4][16][232];   // wave-private P exchange
  const int bh = blockIdx.x;
  const int b = bh / H, h = bh - b * H;
  const int tid = threadIdx.x, lane = tid & 63, w = tid >> 6;
  const int rsel = lane & 15, g = lane >> 4;
  const f4 fz = {0.f, 0.f, 0.f, 0.f};

#pragma unroll
  for (int t = 0; t < 6; t++) {
    int idx = t * 64 + lane;                 // zero pad cols 208..231
    Pl[w][idx / 24][208 + idx % 24] = 0;
  }

  const ushort* Qs = Qh + (size_t)bh * S * DH;
  const ushort* Ks = Kh + (size_t)bh * S * DH;
  const ushort* Vs = Vt + (size_t)bh * DH * SP;

  for (int qt = w; qt < 13; qt += 4) {
    const int q0 = qt * 16;
    int qrow = q0 + rsel; if (qrow > S - 1) qrow = S - 1;
    const bf8 aq0 = ld16(Qs + qrow * DH + g * 8);
    const bf8 aq1 = ld16(Qs + qrow * DH + 32 + g * 8);

    f4 sc[13];
#pragma unroll
    for (int kt = 0; kt < 13; kt++) {
      int key = kt * 16 + rsel; if (key > S - 1) key = S - 1;
      const bf8 bk0 = ld16(Ks + key * DH + g * 8);
      const bf8 bk1 = ld16(Ks + key * DH + 32 + g * 8);
      f4 a = fz;
      a = __builtin_amdgcn_mfma_f32_16x16x32_bf16(aq0, bk0, a, 0, 0, 0);
      a = __builtin_amdgcn_mfma_f32_16x16x32_bf16(aq1, bk1, a, 0, 0, 0);
      sc[kt] = a * 0.125f;
    }

    float mx[4] = {-1e30f, -1e30f, -1e30f, -1e30f};
#pragma unroll
    for (int kt = 0; kt < 13; kt++) {
      const bool vmask = (kt * 16 + rsel) < S;
#pragma unroll
      for (int r = 0; r < 4; r++)
        if (vmask) mx[r] = fmaxf(mx[r], sc[kt][r]);
    }
#pragma unroll
    for (int d = 1; d < 16; d <<= 1)
#pragma unroll
      for (int r = 0; r < 4; r++) mx[r] = fmaxf(mx[r], __shfl_xor(mx[r], d));
    float sm[4] = {0.f, 0.f, 0.f, 0.f};
#pragma unroll
    for (int kt = 0; kt < 13; kt++) {
      const bool vmask = (kt * 16 + rsel) < S;
#pragma unroll
      for (int r = 0; r < 4; r++) {
        const float p = vmask ? exp2f((sc[kt][r] - mx[r]) * 1.44269504f) : 0.f;
        sc[kt][r] = p;
        sm[r] += p;
      }
    }
#pragma unroll
    for (int d = 1; d < 16; d <<= 1)
#pragma unroll
      for (int r = 0; r < 4; r++) sm[r] += __shfl_xor(sm[r], d);

    if (qt == 0 && g == 0) {
      const float inv0 = 1.f / sm[0];
#pragma unroll
      for (int kt = 0; kt < 13; kt++) {
        const int key = kt * 16 + rsel;
        if (key >= 1 && key < S)
          outcls[(size_t)bh * 196 + key - 1] = sc[kt][0] * inv0;
      }
    }

#pragma unroll
    for (int kt = 0; kt < 13; kt++)
#pragma unroll
      for (int r = 0; r < 4; r++)
        Pl[w][g * 4 + r][kt * 16 + rsel] = f2bf(sc[kt][r]);

    bf8 pa[7];
#pragma unroll
    for (int kc = 0; kc < 7; kc++)
      pa[kc] = ld16(&Pl[w][rsel][kc * 32 + g * 8]);
    float inv[4];
#pragma unroll
    for (int r = 0; r < 4; r++) inv[r] = 1.f / sm[r];
#pragma unroll
    for (int nt = 0; nt < 4; nt++) {
      f4 x = fz;
#pragma unroll
      for (int kc = 0; kc < 7; kc++) {
        const bf8 bv = ld16(Vs + (nt * 16 + rsel) * SP + kc * 32 + g * 8);
        x = __builtin_amdgcn_mfma_f32_16x16x32_bf16(pa[kc], bv, x, 0, 0, 0);
      }
#pragma unroll
      for (int r = 0; r < 4; r++) {
        const int s_ = q0 + g * 4 + r;
        if (s_ < S)
          xh[((size_t)b * S + s_) * Dm + h * DH + nt * 16 + rsel] = f2bf(x[r] * inv[r]);
      }
    }
  }
}

// ---------------------------------------------------------------- launch
extern "C" void kernel_launch(void* const* d_in, const int* in_sizes, int n_in,
                              void* d_out, int out_size, void* d_ws, size_t ws_size,
                              hipStream_t stream) {
  (void)in_sizes; (void)n_in; (void)out_size; (void)ws_size;
  const float* q  = (const float*)d_in[0];
  const float* k  = (const float*)d_in[1];
  const float* v  = (const float*)d_in[2];
  const float* wq = (const float*)d_in[3];
  const float* wk = (const float*)d_in[4];
  const float* wv = (const float*)d_in[5];
  const float* wo = (const float*)d_in[6];

  uint8_t* ws = (uint8_t*)d_ws;
  ushort* qb = (ushort*)ws;                 // [M x D] bf16, later reused as xh
  ushort* kb = qb + (size_t)MD;
  ushort* vb = kb + (size_t)MD;
  ushort* wb = vb + (size_t)MD;             // 4 x [768 x 768] bf16
  ushort* Qh = wb + 4 * (size_t)WN;         // [B,H,S,DH] bf16 (then Kh)
  ushort* Kh = Qh + (size_t)MD;
  ushort* Vt = Kh + (size_t)MD;             // [B,H,DH,SP] bf16
  ushort* xh = qb;                          // reuse after projections consumed

  float* out    = (float*)d_out;
  float* outcls = out + (size_t)MD;

  hipMemsetAsync(Vt, 0, (size_t)Bn * H * DH * SP * sizeof(ushort), stream);

  constexpr int CONV_BLOCKS = (3 * (MD / 4) + 4 * (WN / 4)) / 256;
  convert_all<<<dim3(CONV_BLOCKS), 256, 0, stream>>>(
      (const float4*)q, (const float4*)k, (const float4*)v,
      (const float4*)wq, (const float4*)wk, (const float4*)wv, (const float4*)wo,
      (ushort4*)qb, (ushort4*)kb, (ushort4*)vb, (ushort4*)wb);

  gemmL<0><<<dim3(594, 3), 256, 0, stream>>>(qb, wb, Qh, Vt, nullptr);

  attn_fwd<<<dim3(Bn * H), 256, 0, stream>>>(Qh, Kh, Vt, xh, outcls);

  gemmL<1><<<dim3(594, 1), 256, 0, stream>>>(xh, wb + 3 * (size_t)WN, nullptr, nullptr, out);
}